// Round 2
// baseline (789.171 us; speedup 1.0000x reference)
//
#include <hip/hip_runtime.h>
#include <stdint.h>

// Instant-NGP hash-grid encode, 16 levels, F=2, fp32 — LEVEL-PHASED v2b.
// gridDim.y = 10 phases:
//   y == 0   : dense levels 0..6 (tables total 3.97 MB  <= 4 MB per-XCD L2)
//   y == 1   : dense level 7     (table 3.9 MB          <= 4 MB per-XCD L2)
//   y == 2..9: one hashed level each (table 4 MB = per-XCD L2 size)
// Every phase's gather working set fits one XCD's L2.
// Streaming traffic (xyz reads, out writes) is non-temporal so it does NOT
// allocate in L2 and cannot evict the phase's table (table is exactly L2-sized,
// so any pollution causes refetch — seen as 1.16 GB FETCH_SIZE vs ~0.4 GB
// compulsory in the unsplit version).
// NOTE: __builtin_nontemporal_store rejects HIP_vector_type (float4/float2);
// use clang ext_vector_type typedefs instead.
// All hashed levels have size 524288 = 2^19 -> modulo folds to & 0x7FFFF.

typedef float vf4 __attribute__((ext_vector_type(4)));
typedef float vf2 __attribute__((ext_vector_type(2)));

__device__ __constant__ int kRES[16] = {16,20,25,32,40,50,64,80,101,128,161,203,256,322,406,512};

__device__ __forceinline__ float2 dense_level(const float2* __restrict__ emb,
                                              int res, uint32_t off,
                                              float xn, float yn, float zn)
{
    const float scale = (float)(res - 1);
    const float hi    = (float)(res - 2);

    const float px = xn * scale, py = yn * scale, pz = zn * scale;
    const float fx = fminf(fmaxf(floorf(px), 0.0f), hi);
    const float fy = fminf(fmaxf(floorf(py), 0.0f), hi);
    const float fz = fminf(fmaxf(floorf(pz), 0.0f), hi);
    const float wx1 = px - fx, wy1 = py - fy, wz1 = pz - fz;
    const float wx0 = 1.0f - wx1, wy0 = 1.0f - wy1, wz0 = 1.0f - wz1;
    const uint32_t ix = (uint32_t)fx, iy = (uint32_t)fy, iz = (uint32_t)fz;

    const uint32_t dx = (uint32_t)(res * res);
    const uint32_t dy = (uint32_t)res;
    const uint32_t base = off + ix * dx + iy * dy + iz;

    // issue all 8 gathers before consuming (compiler batches vmcnt waits)
    const float2 e00a = emb[base];           const float2 e00b = emb[base + 1];
    const float2 e01a = emb[base + dy];      const float2 e01b = emb[base + dy + 1];
    const float2 e10a = emb[base + dx];      const float2 e10b = emb[base + dx + 1];
    const float2 e11a = emb[base + dx + dy]; const float2 e11b = emb[base + dx + dy + 1];

    float ax, ay, w;
    w = wx0 * wy0; ax  = w * (wz0 * e00a.x + wz1 * e00b.x); ay  = w * (wz0 * e00a.y + wz1 * e00b.y);
    w = wx0 * wy1; ax += w * (wz0 * e01a.x + wz1 * e01b.x); ay += w * (wz0 * e01a.y + wz1 * e01b.y);
    w = wx1 * wy0; ax += w * (wz0 * e10a.x + wz1 * e10b.x); ay += w * (wz0 * e10a.y + wz1 * e10b.y);
    w = wx1 * wy1; ax += w * (wz0 * e11a.x + wz1 * e11b.x); ay += w * (wz0 * e11a.y + wz1 * e11b.y);
    return make_float2(ax, ay);
}

__global__ __launch_bounds__(256, 8) void hashgrid_phased(
    const float* __restrict__ xyz,
    const float2* __restrict__ emb,
    const float* __restrict__ mn,
    const float* __restrict__ mx,
    float* __restrict__ out,
    int npts)
{
    constexpr uint32_t P1 = 2654435761u, P2 = 805459861u;
    constexpr uint32_t HASH_MASK = 0x7FFFFu;     // 524288 - 1
    constexpr uint32_t HASH_BASE = 1023633u;     // OFFS[8]

    const int b = blockIdx.x * blockDim.x + threadIdx.x;
    if (b >= npts) return;

    const float mn0 = mn[0], mn1 = mn[1], mn2 = mn[2];
    const float inv0 = 1.0f / (mx[0] - mn0);
    const float inv1 = 1.0f / (mx[1] - mn1);
    const float inv2 = 1.0f / (mx[2] - mn2);

    // non-temporal: streamed once per phase, zero reuse inside a phase ->
    // must not evict the phase's L2-resident table
    const float x0 = __builtin_nontemporal_load(&xyz[3 * b + 0]);
    const float x1 = __builtin_nontemporal_load(&xyz[3 * b + 1]);
    const float x2 = __builtin_nontemporal_load(&xyz[3 * b + 2]);
    const float xn = (x0 - mn0) * inv0;
    const float yn = (x1 - mn1) * inv1;
    const float zn = (x2 - mn2) * inv2;

    const int y = blockIdx.y;

    if (y == 0) {
        // ---------------- dense levels 0..6 (3.97 MB total) ----------------
        constexpr int RES[7] = {16,20,25,32,40,50,64};
        constexpr uint32_t OFFS[7] = {0u,4096u,12096u,27721u,60489u,124489u,249489u};
        float o[14];
#pragma unroll
        for (int l = 0; l < 7; ++l) {
            const float2 r = dense_level(emb, RES[l], OFFS[l], xn, yn, zn);
            o[2 * l]     = r.x;
            o[2 * l + 1] = r.y;
        }
        float* op = out + (size_t)b * 32;
        vf4 v0 = {o[0],  o[1],  o[2],  o[3]};
        vf4 v1 = {o[4],  o[5],  o[6],  o[7]};
        vf4 v2 = {o[8],  o[9],  o[10], o[11]};
        vf2 v3 = {o[12], o[13]};
        __builtin_nontemporal_store(v0, (vf4*)(op));
        __builtin_nontemporal_store(v1, (vf4*)(op + 4));
        __builtin_nontemporal_store(v2, (vf4*)(op + 8));
        __builtin_nontemporal_store(v3, (vf2*)(op + 12));
    } else if (y == 1) {
        // ---------------- dense level 7 (3.9 MB) ----------------
        const float2 r = dense_level(emb, 80, 511633u, xn, yn, zn);
        vf2 v = {r.x, r.y};
        __builtin_nontemporal_store(v, (vf2*)(out + (size_t)b * 32 + 14));
    } else {
        // ---------------- one hashed level (8..15), table = 4 MB ----------------
        const int l = y + 6;
        const int res = kRES[l];                        // wave-uniform scalar load
        const uint32_t off = HASH_BASE + (uint32_t)(l - 8) * 524288u;

        const float scale = (float)(res - 1);
        const float hi    = (float)(res - 2);

        const float px = xn * scale, py = yn * scale, pz = zn * scale;
        const float fx = fminf(fmaxf(floorf(px), 0.0f), hi);
        const float fy = fminf(fmaxf(floorf(py), 0.0f), hi);
        const float fz = fminf(fmaxf(floorf(pz), 0.0f), hi);
        const float wx1 = px - fx, wy1 = py - fy, wz1 = pz - fz;
        const float wx0 = 1.0f - wx1, wy0 = 1.0f - wy1, wz0 = 1.0f - wz1;
        const uint32_t ix = (uint32_t)fx, iy = (uint32_t)fy, iz = (uint32_t)fz;

        const uint32_t hx0 = ix,      hx1 = ix + 1u;
        const uint32_t hy0 = iy * P1, hy1 = hy0 + P1;
        const uint32_t hz0 = iz * P2, hz1 = hz0 + P2;

        const uint32_t i000 = ((hx0 ^ hy0 ^ hz0) & HASH_MASK) + off;
        const uint32_t i001 = ((hx0 ^ hy0 ^ hz1) & HASH_MASK) + off;
        const uint32_t i010 = ((hx0 ^ hy1 ^ hz0) & HASH_MASK) + off;
        const uint32_t i011 = ((hx0 ^ hy1 ^ hz1) & HASH_MASK) + off;
        const uint32_t i100 = ((hx1 ^ hy0 ^ hz0) & HASH_MASK) + off;
        const uint32_t i101 = ((hx1 ^ hy0 ^ hz1) & HASH_MASK) + off;
        const uint32_t i110 = ((hx1 ^ hy1 ^ hz0) & HASH_MASK) + off;
        const uint32_t i111 = ((hx1 ^ hy1 ^ hz1) & HASH_MASK) + off;

        // issue all 8 gathers before consuming (compiler batches vmcnt waits)
        const float2 e000 = emb[i000], e001 = emb[i001], e010 = emb[i010], e011 = emb[i011];
        const float2 e100 = emb[i100], e101 = emb[i101], e110 = emb[i110], e111 = emb[i111];

        float ax, ay, w;
        w = wx0 * wy0 * wz0; ax  = w * e000.x; ay  = w * e000.y;
        w = wx0 * wy0 * wz1; ax += w * e001.x; ay += w * e001.y;
        w = wx0 * wy1 * wz0; ax += w * e010.x; ay += w * e010.y;
        w = wx0 * wy1 * wz1; ax += w * e011.x; ay += w * e011.y;
        w = wx1 * wy0 * wz0; ax += w * e100.x; ay += w * e100.y;
        w = wx1 * wy0 * wz1; ax += w * e101.x; ay += w * e101.y;
        w = wx1 * wy1 * wz0; ax += w * e110.x; ay += w * e110.y;
        w = wx1 * wy1 * wz1; ax += w * e111.x; ay += w * e111.y;

        vf2 v = {ax, ay};
        __builtin_nontemporal_store(v, (vf2*)(out + (size_t)b * 32 + 2 * l));
    }
}

extern "C" void kernel_launch(void* const* d_in, const int* in_sizes, int n_in,
                              void* d_out, int out_size, void* d_ws, size_t ws_size,
                              hipStream_t stream) {
    const float*  xyz = (const float*)d_in[0];
    const float2* emb = (const float2*)d_in[1];
    const float*  mn  = (const float*)d_in[2];
    const float*  mx  = (const float*)d_in[3];
    float* out = (float*)d_out;

    const int npts = in_sizes[0] / 3;          // 1<<20
    const int block = 256;
    const int grid_x = (npts + block - 1) / block;

    hipLaunchKernelGGL(hashgrid_phased, dim3(grid_x, 10), dim3(block), 0, stream,
                       xyz, emb, mn, mx, out, npts);
}

// Round 3
// 748.214 us; speedup vs baseline: 1.0547x; 1.0547x over previous
//
#include <hip/hip_runtime.h>
#include <stdint.h>

// Instant-NGP hash-grid encode, 16 levels, F=2, fp32 — v3: CELL-GATHERED DENSE.
//
// Round-2 finding: FETCH_SIZE halved (1.16 GB -> 0.48 GB = compulsory) but time
// was flat -> NOT bandwidth/L2-miss bound. Binding resource is diverged-gather
// line-request throughput (~3 cy per L1-missing lane-request per CU).
// Lever: fewer L1-missing line requests per point.
//
// v3: prep kernel re-layouts the 8 dense levels into "cell-gathered" blocks in
// workspace: all 8 corner float2s of a cell contiguous in one 64 B line-aligned
// block. A point then costs 1 line-request per dense level (4 aligned dwordx4
// loads, 3 L1-hit the same line) instead of ~4.5.
// Hashed levels (8 independent random slots) are the irreducible floor and keep
// the phased L2-resident scheme from v2b.
// Exact fp32 copy -> no precision change. Falls back to v2b path if ws too small.

typedef float vf4 __attribute__((ext_vector_type(4)));
typedef float vf2 __attribute__((ext_vector_type(2)));

__device__ __constant__ int kRES[16] = {16,20,25,32,40,50,64,80,101,128,161,203,256,322,406,512};

// dense-level geometry (levels 0..7)
#define D_RES   {16,20,25,32,40,50,64,80}
#define D_OFF   {0u,4096u,12096u,27721u,60489u,124489u,249489u,511633u}
// cells per level = (res-1)^3 ; cumulative cell base
#define D_CBASE {0u,3375u,10234u,24058u,53849u,113168u,230817u,480864u}
#define D_CTOT  973903u
// quarter-cell tasks = 4 * cells
#define D_QTOT  3895612u

__device__ __constant__ uint32_t kCB[9] = {0u,3375u,10234u,24058u,53849u,113168u,230817u,480864u,973903u};
__device__ __constant__ int      kDR[8] = D_RES;
__device__ __constant__ uint32_t kDO[8] = D_OFF;

// ---------------------------------------------------------------------------
// prep: build cell-gathered dense tables in ws.
// one thread per quarter-cell: copies corner pair (2p, 2p+1) = (bx,by,z=0/1).
// ---------------------------------------------------------------------------
__global__ __launch_bounds__(256) void prep_cells(
    const float2* __restrict__ emb, float2* __restrict__ ws)
{
    const uint32_t tid = blockIdx.x * 256u + threadIdx.x;
    if (tid >= D_QTOT) return;

    const uint32_t cell = tid >> 2;
    const uint32_t part = tid & 3u;          // (bx<<1)|by

    // find level
    int l = 0;
#pragma unroll
    for (int i = 1; i < 8; ++i) l += (cell >= kCB[i]);

    const uint32_t c  = cell - kCB[l];
    const int res = kDR[l];
    const uint32_t r1 = (uint32_t)(res - 1);

    const uint32_t cz  = c % r1;
    const uint32_t t   = c / r1;
    const uint32_t cy  = t % r1;
    const uint32_t cx  = t / r1;

    const uint32_t bx = part >> 1, by = part & 1u;
    const uint32_t src = kDO[l] + (cx + bx) * (uint32_t)(res * res)
                                + (cy + by) * (uint32_t)res + cz;

    const float2 e0 = emb[src];        // z = 0
    const float2 e1 = emb[src + 1];    // z = 1

    // dst block: cell*8 float2s, this thread writes float2s [2p, 2p+1] -> one 16B store
    vf4 v = {e0.x, e0.y, e1.x, e1.y};
    __builtin_nontemporal_store(v, (vf4*)(ws + ((size_t)cell * 8u + part * 2u)));
}

// ---------------------------------------------------------------------------
// main: gridDim.y = 9 phases
//   y == 0   : all 8 dense levels via cell-gathered ws (1 line-req per level)
//   y == 1..8: one hashed level each (table 4 MB = per-XCD L2)
// ---------------------------------------------------------------------------
__global__ __launch_bounds__(256, 8) void hashgrid_cell(
    const float* __restrict__ xyz,
    const float2* __restrict__ emb,
    const float2* __restrict__ ws,
    const float* __restrict__ mn,
    const float* __restrict__ mx,
    float* __restrict__ out,
    int npts)
{
    constexpr uint32_t P1 = 2654435761u, P2 = 805459861u;
    constexpr uint32_t HASH_MASK = 0x7FFFFu;
    constexpr uint32_t HASH_BASE = 1023633u;

    const int b = blockIdx.x * blockDim.x + threadIdx.x;
    if (b >= npts) return;

    const float mn0 = mn[0], mn1 = mn[1], mn2 = mn[2];
    const float inv0 = 1.0f / (mx[0] - mn0);
    const float inv1 = 1.0f / (mx[1] - mn1);
    const float inv2 = 1.0f / (mx[2] - mn2);

    const float xn = (__builtin_nontemporal_load(&xyz[3 * b + 0]) - mn0) * inv0;
    const float yn = (__builtin_nontemporal_load(&xyz[3 * b + 1]) - mn1) * inv1;
    const float zn = (__builtin_nontemporal_load(&xyz[3 * b + 2]) - mn2) * inv2;

    const int y = blockIdx.y;

    if (y == 0) {
        // ---------------- dense levels 0..7, cell-gathered ----------------
        constexpr int RES[8] = D_RES;
        constexpr uint32_t CB[8] = D_CBASE;
        float o[16];
#pragma unroll
        for (int l = 0; l < 8; ++l) {
            const int res = RES[l];
            const uint32_t r1 = (uint32_t)(res - 1);
            const float scale = (float)(res - 1);
            const float hi    = (float)(res - 2);

            const float px = xn * scale, py = yn * scale, pz = zn * scale;
            const float fx = fminf(fmaxf(floorf(px), 0.0f), hi);
            const float fy = fminf(fmaxf(floorf(py), 0.0f), hi);
            const float fz = fminf(fmaxf(floorf(pz), 0.0f), hi);
            const float wx1 = px - fx, wy1 = py - fy, wz1 = pz - fz;
            const float wx0 = 1.0f - wx1, wy0 = 1.0f - wy1, wz0 = 1.0f - wz1;
            const uint32_t ix = (uint32_t)fx, iy = (uint32_t)fy, iz = (uint32_t)fz;

            const uint32_t cell = CB[l] + (ix * r1 + iy) * r1 + iz;
            const vf4* blk = (const vf4*)(ws + (size_t)cell * 8u);
            // q0={e000,e001} q1={e010,e011} q2={e100,e101} q3={e110,e111}
            const vf4 q0 = blk[0], q1 = blk[1], q2 = blk[2], q3 = blk[3];

            float ax, ay, w;
            w = wx0 * wy0; ax  = w * (wz0 * q0.x + wz1 * q0.z); ay  = w * (wz0 * q0.y + wz1 * q0.w);
            w = wx0 * wy1; ax += w * (wz0 * q1.x + wz1 * q1.z); ay += w * (wz0 * q1.y + wz1 * q1.w);
            w = wx1 * wy0; ax += w * (wz0 * q2.x + wz1 * q2.z); ay += w * (wz0 * q2.y + wz1 * q2.w);
            w = wx1 * wy1; ax += w * (wz0 * q3.x + wz1 * q3.z); ay += w * (wz0 * q3.y + wz1 * q3.w);
            o[2 * l]     = ax;
            o[2 * l + 1] = ay;
        }
        float* op = out + (size_t)b * 32;
#pragma unroll
        for (int i = 0; i < 4; ++i) {
            vf4 v = {o[4 * i + 0], o[4 * i + 1], o[4 * i + 2], o[4 * i + 3]};
            __builtin_nontemporal_store(v, (vf4*)(op + 4 * i));
        }
    } else {
        // ---------------- one hashed level (8..15), table = 4 MB ----------------
        const int l = y + 7;
        const int res = kRES[l];
        const uint32_t off = HASH_BASE + (uint32_t)(l - 8) * 524288u;

        const float scale = (float)(res - 1);
        const float hi    = (float)(res - 2);

        const float px = xn * scale, py = yn * scale, pz = zn * scale;
        const float fx = fminf(fmaxf(floorf(px), 0.0f), hi);
        const float fy = fminf(fmaxf(floorf(py), 0.0f), hi);
        const float fz = fminf(fmaxf(floorf(pz), 0.0f), hi);
        const float wx1 = px - fx, wy1 = py - fy, wz1 = pz - fz;
        const float wx0 = 1.0f - wx1, wy0 = 1.0f - wy1, wz0 = 1.0f - wz1;
        const uint32_t ix = (uint32_t)fx, iy = (uint32_t)fy, iz = (uint32_t)fz;

        const uint32_t hx0 = ix,      hx1 = ix + 1u;
        const uint32_t hy0 = iy * P1, hy1 = hy0 + P1;
        const uint32_t hz0 = iz * P2, hz1 = hz0 + P2;

        const uint32_t i000 = ((hx0 ^ hy0 ^ hz0) & HASH_MASK) + off;
        const uint32_t i001 = ((hx0 ^ hy0 ^ hz1) & HASH_MASK) + off;
        const uint32_t i010 = ((hx0 ^ hy1 ^ hz0) & HASH_MASK) + off;
        const uint32_t i011 = ((hx0 ^ hy1 ^ hz1) & HASH_MASK) + off;
        const uint32_t i100 = ((hx1 ^ hy0 ^ hz0) & HASH_MASK) + off;
        const uint32_t i101 = ((hx1 ^ hy0 ^ hz1) & HASH_MASK) + off;
        const uint32_t i110 = ((hx1 ^ hy1 ^ hz0) & HASH_MASK) + off;
        const uint32_t i111 = ((hx1 ^ hy1 ^ hz1) & HASH_MASK) + off;

        const float2 e000 = emb[i000], e001 = emb[i001], e010 = emb[i010], e011 = emb[i011];
        const float2 e100 = emb[i100], e101 = emb[i101], e110 = emb[i110], e111 = emb[i111];

        float ax, ay, w;
        w = wx0 * wy0 * wz0; ax  = w * e000.x; ay  = w * e000.y;
        w = wx0 * wy0 * wz1; ax += w * e001.x; ay += w * e001.y;
        w = wx0 * wy1 * wz0; ax += w * e010.x; ay += w * e010.y;
        w = wx0 * wy1 * wz1; ax += w * e011.x; ay += w * e011.y;
        w = wx1 * wy0 * wz0; ax += w * e100.x; ay += w * e100.y;
        w = wx1 * wy0 * wz1; ax += w * e101.x; ay += w * e101.y;
        w = wx1 * wy1 * wz0; ax += w * e110.x; ay += w * e110.y;
        w = wx1 * wy1 * wz1; ax += w * e111.x; ay += w * e111.y;

        vf2 v = {ax, ay};
        __builtin_nontemporal_store(v, (vf2*)(out + (size_t)b * 32 + 2 * l));
    }
}

// ---------------------------------------------------------------------------
// fallback (v2b): direct dense gathers, used when ws is too small
// ---------------------------------------------------------------------------
__global__ __launch_bounds__(256, 8) void hashgrid_direct(
    const float* __restrict__ xyz,
    const float2* __restrict__ emb,
    const float* __restrict__ mn,
    const float* __restrict__ mx,
    float* __restrict__ out,
    int npts)
{
    constexpr uint32_t P1 = 2654435761u, P2 = 805459861u;
    constexpr uint32_t HASH_MASK = 0x7FFFFu;
    constexpr uint32_t HASH_BASE = 1023633u;

    const int b = blockIdx.x * blockDim.x + threadIdx.x;
    if (b >= npts) return;

    const float mn0 = mn[0], mn1 = mn[1], mn2 = mn[2];
    const float inv0 = 1.0f / (mx[0] - mn0);
    const float inv1 = 1.0f / (mx[1] - mn1);
    const float inv2 = 1.0f / (mx[2] - mn2);

    const float xn = (xyz[3 * b + 0] - mn0) * inv0;
    const float yn = (xyz[3 * b + 1] - mn1) * inv1;
    const float zn = (xyz[3 * b + 2] - mn2) * inv2;

    const int y = blockIdx.y;

    if (y == 0) {
        constexpr int RES[8] = D_RES;
        constexpr uint32_t OFFS[8] = D_OFF;
        float o[16];
#pragma unroll
        for (int l = 0; l < 8; ++l) {
            const int res = RES[l];
            const uint32_t off = OFFS[l];
            const float scale = (float)(res - 1);
            const float hi = (float)(res - 2);

            const float px = xn * scale, py = yn * scale, pz = zn * scale;
            const float fx = fminf(fmaxf(floorf(px), 0.0f), hi);
            const float fy = fminf(fmaxf(floorf(py), 0.0f), hi);
            const float fz = fminf(fmaxf(floorf(pz), 0.0f), hi);
            const float wx1 = px - fx, wy1 = py - fy, wz1 = pz - fz;
            const float wx0 = 1.0f - wx1, wy0 = 1.0f - wy1, wz0 = 1.0f - wz1;
            const uint32_t ix = (uint32_t)fx, iy = (uint32_t)fy, iz = (uint32_t)fz;

            const uint32_t dx = (uint32_t)(res * res);
            const uint32_t dy = (uint32_t)res;
            const uint32_t base = off + ix * dx + iy * dy + iz;

            float ax = 0.0f, ay = 0.0f;
            {
                float2 e0 = emb[base];           float2 e1 = emb[base + 1];
                float wxy = wx0 * wy0;
                ax += wxy * (wz0 * e0.x + wz1 * e1.x); ay += wxy * (wz0 * e0.y + wz1 * e1.y);
            }
            {
                float2 e0 = emb[base + dy];      float2 e1 = emb[base + dy + 1];
                float wxy = wx0 * wy1;
                ax += wxy * (wz0 * e0.x + wz1 * e1.x); ay += wxy * (wz0 * e0.y + wz1 * e1.y);
            }
            {
                float2 e0 = emb[base + dx];      float2 e1 = emb[base + dx + 1];
                float wxy = wx1 * wy0;
                ax += wxy * (wz0 * e0.x + wz1 * e1.x); ay += wxy * (wz0 * e0.y + wz1 * e1.y);
            }
            {
                float2 e0 = emb[base + dx + dy]; float2 e1 = emb[base + dx + dy + 1];
                float wxy = wx1 * wy1;
                ax += wxy * (wz0 * e0.x + wz1 * e1.x); ay += wxy * (wz0 * e0.y + wz1 * e1.y);
            }
            o[2 * l]     = ax;
            o[2 * l + 1] = ay;
        }
        float4* ov = (float4*)(out + (size_t)b * 32);
#pragma unroll
        for (int i = 0; i < 4; ++i)
            ov[i] = make_float4(o[4 * i + 0], o[4 * i + 1], o[4 * i + 2], o[4 * i + 3]);
    } else {
        const int l = y + 7;
        const int res = kRES[l];
        const uint32_t off = HASH_BASE + (uint32_t)(l - 8) * 524288u;

        const float scale = (float)(res - 1);
        const float hi = (float)(res - 2);

        const float px = xn * scale, py = yn * scale, pz = zn * scale;
        const float fx = fminf(fmaxf(floorf(px), 0.0f), hi);
        const float fy = fminf(fmaxf(floorf(py), 0.0f), hi);
        const float fz = fminf(fmaxf(floorf(pz), 0.0f), hi);
        const float wx1 = px - fx, wy1 = py - fy, wz1 = pz - fz;
        const float wx0 = 1.0f - wx1, wy0 = 1.0f - wy1, wz0 = 1.0f - wz1;
        const uint32_t ix = (uint32_t)fx, iy = (uint32_t)fy, iz = (uint32_t)fz;

        const uint32_t hx0 = ix,      hx1 = ix + 1u;
        const uint32_t hy0 = iy * P1, hy1 = hy0 + P1;
        const uint32_t hz0 = iz * P2, hz1 = hz0 + P2;

        const uint32_t i000 = ((hx0 ^ hy0 ^ hz0) & HASH_MASK) + off;
        const uint32_t i001 = ((hx0 ^ hy0 ^ hz1) & HASH_MASK) + off;
        const uint32_t i010 = ((hx0 ^ hy1 ^ hz0) & HASH_MASK) + off;
        const uint32_t i011 = ((hx0 ^ hy1 ^ hz1) & HASH_MASK) + off;
        const uint32_t i100 = ((hx1 ^ hy0 ^ hz0) & HASH_MASK) + off;
        const uint32_t i101 = ((hx1 ^ hy0 ^ hz1) & HASH_MASK) + off;
        const uint32_t i110 = ((hx1 ^ hy1 ^ hz0) & HASH_MASK) + off;
        const uint32_t i111 = ((hx1 ^ hy1 ^ hz1) & HASH_MASK) + off;

        const float2 e000 = emb[i000], e001 = emb[i001], e010 = emb[i010], e011 = emb[i011];
        const float2 e100 = emb[i100], e101 = emb[i101], e110 = emb[i110], e111 = emb[i111];

        float ax, ay, w;
        w = wx0 * wy0 * wz0; ax  = w * e000.x; ay  = w * e000.y;
        w = wx0 * wy0 * wz1; ax += w * e001.x; ay += w * e001.y;
        w = wx0 * wy1 * wz0; ax += w * e010.x; ay += w * e010.y;
        w = wx0 * wy1 * wz1; ax += w * e011.x; ay += w * e011.y;
        w = wx1 * wy0 * wz0; ax += w * e100.x; ay += w * e100.y;
        w = wx1 * wy0 * wz1; ax += w * e101.x; ay += w * e101.y;
        w = wx1 * wy1 * wz0; ax += w * e110.x; ay += w * e110.y;
        w = wx1 * wy1 * wz1; ax += w * e111.x; ay += w * e111.y;

        float2* op = (float2*)(out + (size_t)b * 32 + 2 * l);
        *op = make_float2(ax, ay);
    }
}

extern "C" void kernel_launch(void* const* d_in, const int* in_sizes, int n_in,
                              void* d_out, int out_size, void* d_ws, size_t ws_size,
                              hipStream_t stream) {
    const float*  xyz = (const float*)d_in[0];
    const float2* emb = (const float2*)d_in[1];
    const float*  mn  = (const float*)d_in[2];
    const float*  mx  = (const float*)d_in[3];
    float* out = (float*)d_out;

    const int npts = in_sizes[0] / 3;          // 1<<20
    const int block = 256;
    const int grid_x = (npts + block - 1) / block;

    const size_t ws_needed = (size_t)D_CTOT * 64u;   // 62.3 MB

    if (ws_size >= ws_needed && d_ws != nullptr) {
        float2* ws = (float2*)d_ws;
        const int prep_grid = (int)((D_QTOT + 255u) / 256u);
        hipLaunchKernelGGL(prep_cells, dim3(prep_grid), dim3(256), 0, stream, emb, ws);
        hipLaunchKernelGGL(hashgrid_cell, dim3(grid_x, 9), dim3(block), 0, stream,
                           xyz, emb, ws, mn, mx, out, npts);
    } else {
        hipLaunchKernelGGL(hashgrid_direct, dim3(grid_x, 9), dim3(block), 0, stream,
                           xyz, emb, mn, mx, out, npts);
    }
}

// Round 4
// 738.536 us; speedup vs baseline: 1.0686x; 1.0131x over previous
//
#include <hip/hip_runtime.h>
#include <stdint.h>

// Instant-NGP hash-grid encode, 16 levels, F=2, fp32 — v4.
//
// Evidence so far: NOT bandwidth-bound (FETCH halved -> time flat, r2) and NOT
// L2-hit-rate-bound (FETCH rose -> time fell, r3). Binding resource: diverged
// vector-memory line-request throughput (~2.7 cy/request/CU). Currency =
// diverged requests per point.
//
// v4 changes vs v3:
//  1. prep kernel: per-level compile-time resolution (blockIdx.y = level) so
//     cell %/ (res-1) compile to magic-multiplies. v3 used runtime divisors ->
//     ~165 us of pure integer-division. Predicted ~25 us.
//  2. hashed levels processed in PAIRS (4 phases instead of 8): merges the two
//     8B output stores into one dwordx4 (-4 diverged store-req/pt), halves xyz
//     re-reads and phase overhead. Pair working set = 8 MB on 4 MB L2; extra
//     misses are L3-backed and time-free per r2/r3 evidence.
//
// Dense levels stay cell-gathered in workspace (64 B/cell, line-aligned:
// 4 dwordx4 = 1 unique line per level instead of ~4.5).

typedef float vf4 __attribute__((ext_vector_type(4)));
typedef float vf2 __attribute__((ext_vector_type(2)));

__device__ __constant__ int kRES[16] = {16,20,25,32,40,50,64,80,101,128,161,203,256,322,406,512};

#define D_RES   {16,20,25,32,40,50,64,80}
#define D_OFF   {0u,4096u,12096u,27721u,60489u,124489u,249489u,511633u}
#define D_CBASE {0u,3375u,10234u,24058u,53849u,113168u,230817u,480864u}
#define D_CTOT  973903u
#define PREP_MAXTASK 1972156u   // 4 * (79^3), level 7

// ---------------------------------------------------------------------------
// prep: build cell-gathered dense tables in ws. blockIdx.y = level, res is a
// compile-time constant -> %/ by (RES-1) become magic multiplies.
// one thread per quarter-cell: copies corner pair (bx,by, z=0/1) as one 16B st.
// ---------------------------------------------------------------------------
template<int RES, uint32_t OFF, uint32_t CBASE>
__device__ __forceinline__ void prep_level(const float2* __restrict__ emb,
                                           float2* __restrict__ ws,
                                           uint32_t tid)
{
    constexpr uint32_t r1 = (uint32_t)(RES - 1);
    constexpr uint32_t ntask = r1 * r1 * r1 * 4u;
    if (tid >= ntask) return;

    const uint32_t cell = tid >> 2;
    const uint32_t part = tid & 3u;              // (bx<<1)|by

    const uint32_t cz = cell % r1;               // compile-time divisor
    const uint32_t t  = cell / r1;
    const uint32_t cy = t % r1;
    const uint32_t cx = t / r1;

    const uint32_t bx = part >> 1, by = part & 1u;
    const uint32_t src = OFF + (cx + bx) * (uint32_t)(RES * RES)
                             + (cy + by) * (uint32_t)RES + cz;

    const float2 e0 = emb[src];                  // z = 0
    const float2 e1 = emb[src + 1];              // z = 1

    vf4 v = {e0.x, e0.y, e1.x, e1.y};
    __builtin_nontemporal_store(v, (vf4*)(ws + ((size_t)(CBASE + cell) * 8u + part * 2u)));
}

__global__ __launch_bounds__(256) void prep_cells(
    const float2* __restrict__ emb, float2* __restrict__ ws)
{
    const uint32_t tid = blockIdx.x * 256u + threadIdx.x;
    switch (blockIdx.y) {
        case 0: prep_level<16,      0u,      0u>(emb, ws, tid); break;
        case 1: prep_level<20,   4096u,   3375u>(emb, ws, tid); break;
        case 2: prep_level<25,  12096u,  10234u>(emb, ws, tid); break;
        case 3: prep_level<32,  27721u,  24058u>(emb, ws, tid); break;
        case 4: prep_level<40,  60489u,  53849u>(emb, ws, tid); break;
        case 5: prep_level<50, 124489u, 113168u>(emb, ws, tid); break;
        case 6: prep_level<64, 249489u, 230817u>(emb, ws, tid); break;
        case 7: prep_level<80, 511633u, 480864u>(emb, ws, tid); break;
    }
}

// ---------------------------------------------------------------------------
// hashed-level helper (levels 8..15): 8 independent random 8B gathers
// ---------------------------------------------------------------------------
__device__ __forceinline__ float2 hash_level(const float2* __restrict__ emb,
                                             int l, float xn, float yn, float zn)
{
    constexpr uint32_t P1 = 2654435761u, P2 = 805459861u;
    constexpr uint32_t HASH_MASK = 0x7FFFFu;     // 524288 - 1
    constexpr uint32_t HASH_BASE = 1023633u;     // OFFS[8]

    const int res = kRES[l];                     // wave-uniform
    const uint32_t off = HASH_BASE + (uint32_t)(l - 8) * 524288u;

    const float scale = (float)(res - 1);
    const float hi    = (float)(res - 2);

    const float px = xn * scale, py = yn * scale, pz = zn * scale;
    const float fx = fminf(fmaxf(floorf(px), 0.0f), hi);
    const float fy = fminf(fmaxf(floorf(py), 0.0f), hi);
    const float fz = fminf(fmaxf(floorf(pz), 0.0f), hi);
    const float wx1 = px - fx, wy1 = py - fy, wz1 = pz - fz;
    const float wx0 = 1.0f - wx1, wy0 = 1.0f - wy1, wz0 = 1.0f - wz1;
    const uint32_t ix = (uint32_t)fx, iy = (uint32_t)fy, iz = (uint32_t)fz;

    const uint32_t hx0 = ix,      hx1 = ix + 1u;
    const uint32_t hy0 = iy * P1, hy1 = hy0 + P1;
    const uint32_t hz0 = iz * P2, hz1 = hz0 + P2;

    const uint32_t i000 = ((hx0 ^ hy0 ^ hz0) & HASH_MASK) + off;
    const uint32_t i001 = ((hx0 ^ hy0 ^ hz1) & HASH_MASK) + off;
    const uint32_t i010 = ((hx0 ^ hy1 ^ hz0) & HASH_MASK) + off;
    const uint32_t i011 = ((hx0 ^ hy1 ^ hz1) & HASH_MASK) + off;
    const uint32_t i100 = ((hx1 ^ hy0 ^ hz0) & HASH_MASK) + off;
    const uint32_t i101 = ((hx1 ^ hy0 ^ hz1) & HASH_MASK) + off;
    const uint32_t i110 = ((hx1 ^ hy1 ^ hz0) & HASH_MASK) + off;
    const uint32_t i111 = ((hx1 ^ hy1 ^ hz1) & HASH_MASK) + off;

    const float2 e000 = emb[i000], e001 = emb[i001], e010 = emb[i010], e011 = emb[i011];
    const float2 e100 = emb[i100], e101 = emb[i101], e110 = emb[i110], e111 = emb[i111];

    float ax, ay, w;
    w = wx0 * wy0 * wz0; ax  = w * e000.x; ay  = w * e000.y;
    w = wx0 * wy0 * wz1; ax += w * e001.x; ay += w * e001.y;
    w = wx0 * wy1 * wz0; ax += w * e010.x; ay += w * e010.y;
    w = wx0 * wy1 * wz1; ax += w * e011.x; ay += w * e011.y;
    w = wx1 * wy0 * wz0; ax += w * e100.x; ay += w * e100.y;
    w = wx1 * wy0 * wz1; ax += w * e101.x; ay += w * e101.y;
    w = wx1 * wy1 * wz0; ax += w * e110.x; ay += w * e110.y;
    w = wx1 * wy1 * wz1; ax += w * e111.x; ay += w * e111.y;
    return make_float2(ax, ay);
}

// ---------------------------------------------------------------------------
// main: gridDim.y = 5 phases
//   y == 0   : all 8 dense levels via cell-gathered ws (1 unique line/level)
//   y == 1..4: one PAIR of hashed levels (8+2(y-1), 9+2(y-1)); outputs merge
//              into a single dwordx4 store.
// ---------------------------------------------------------------------------
__global__ __launch_bounds__(256, 8) void hashgrid_cell(
    const float* __restrict__ xyz,
    const float2* __restrict__ emb,
    const float2* __restrict__ ws,
    const float* __restrict__ mn,
    const float* __restrict__ mx,
    float* __restrict__ out,
    int npts)
{
    const int b = blockIdx.x * blockDim.x + threadIdx.x;
    if (b >= npts) return;

    const float mn0 = mn[0], mn1 = mn[1], mn2 = mn[2];
    const float inv0 = 1.0f / (mx[0] - mn0);
    const float inv1 = 1.0f / (mx[1] - mn1);
    const float inv2 = 1.0f / (mx[2] - mn2);

    const float xn = (__builtin_nontemporal_load(&xyz[3 * b + 0]) - mn0) * inv0;
    const float yn = (__builtin_nontemporal_load(&xyz[3 * b + 1]) - mn1) * inv1;
    const float zn = (__builtin_nontemporal_load(&xyz[3 * b + 2]) - mn2) * inv2;

    const int y = blockIdx.y;

    if (y == 0) {
        // ---------------- dense levels 0..7, cell-gathered ----------------
        constexpr int RES[8] = D_RES;
        constexpr uint32_t CB[8] = D_CBASE;
        float o[16];
#pragma unroll
        for (int l = 0; l < 8; ++l) {
            const int res = RES[l];
            const uint32_t r1 = (uint32_t)(res - 1);
            const float scale = (float)(res - 1);
            const float hi    = (float)(res - 2);

            const float px = xn * scale, py = yn * scale, pz = zn * scale;
            const float fx = fminf(fmaxf(floorf(px), 0.0f), hi);
            const float fy = fminf(fmaxf(floorf(py), 0.0f), hi);
            const float fz = fminf(fmaxf(floorf(pz), 0.0f), hi);
            const float wx1 = px - fx, wy1 = py - fy, wz1 = pz - fz;
            const float wx0 = 1.0f - wx1, wy0 = 1.0f - wy1, wz0 = 1.0f - wz1;
            const uint32_t ix = (uint32_t)fx, iy = (uint32_t)fy, iz = (uint32_t)fz;

            const uint32_t cell = CB[l] + (ix * r1 + iy) * r1 + iz;
            const vf4* blk = (const vf4*)(ws + (size_t)cell * 8u);
            // q0={e000,e001} q1={e010,e011} q2={e100,e101} q3={e110,e111}
            const vf4 q0 = blk[0], q1 = blk[1], q2 = blk[2], q3 = blk[3];

            float ax, ay, w;
            w = wx0 * wy0; ax  = w * (wz0 * q0.x + wz1 * q0.z); ay  = w * (wz0 * q0.y + wz1 * q0.w);
            w = wx0 * wy1; ax += w * (wz0 * q1.x + wz1 * q1.z); ay += w * (wz0 * q1.y + wz1 * q1.w);
            w = wx1 * wy0; ax += w * (wz0 * q2.x + wz1 * q2.z); ay += w * (wz0 * q2.y + wz1 * q2.w);
            w = wx1 * wy1; ax += w * (wz0 * q3.x + wz1 * q3.z); ay += w * (wz0 * q3.y + wz1 * q3.w);
            o[2 * l]     = ax;
            o[2 * l + 1] = ay;
        }
        float* op = out + (size_t)b * 32;
#pragma unroll
        for (int i = 0; i < 4; ++i) {
            vf4 v = {o[4 * i + 0], o[4 * i + 1], o[4 * i + 2], o[4 * i + 3]};
            __builtin_nontemporal_store(v, (vf4*)(op + 4 * i));
        }
    } else {
        // ---------------- hashed level pair (l0, l0+1) ----------------
        const int l0 = 6 + 2 * y;                 // y=1->8, 2->10, 3->12, 4->14
        const float2 ra = hash_level(emb, l0,     xn, yn, zn);
        const float2 rb = hash_level(emb, l0 + 1, xn, yn, zn);
        vf4 v = {ra.x, ra.y, rb.x, rb.y};
        __builtin_nontemporal_store(v, (vf4*)(out + (size_t)b * 32 + 2 * l0));
    }
}

// ---------------------------------------------------------------------------
// fallback: direct dense gathers (no workspace), 9 phases — v2b structure
// ---------------------------------------------------------------------------
__global__ __launch_bounds__(256, 8) void hashgrid_direct(
    const float* __restrict__ xyz,
    const float2* __restrict__ emb,
    const float* __restrict__ mn,
    const float* __restrict__ mx,
    float* __restrict__ out,
    int npts)
{
    const int b = blockIdx.x * blockDim.x + threadIdx.x;
    if (b >= npts) return;

    const float mn0 = mn[0], mn1 = mn[1], mn2 = mn[2];
    const float inv0 = 1.0f / (mx[0] - mn0);
    const float inv1 = 1.0f / (mx[1] - mn1);
    const float inv2 = 1.0f / (mx[2] - mn2);

    const float xn = (xyz[3 * b + 0] - mn0) * inv0;
    const float yn = (xyz[3 * b + 1] - mn1) * inv1;
    const float zn = (xyz[3 * b + 2] - mn2) * inv2;

    const int y = blockIdx.y;

    if (y == 0) {
        constexpr int RES[8] = D_RES;
        constexpr uint32_t OFFS[8] = D_OFF;
        float o[16];
#pragma unroll
        for (int l = 0; l < 8; ++l) {
            const int res = RES[l];
            const uint32_t off = OFFS[l];
            const float scale = (float)(res - 1);
            const float hi = (float)(res - 2);

            const float px = xn * scale, py = yn * scale, pz = zn * scale;
            const float fx = fminf(fmaxf(floorf(px), 0.0f), hi);
            const float fy = fminf(fmaxf(floorf(py), 0.0f), hi);
            const float fz = fminf(fmaxf(floorf(pz), 0.0f), hi);
            const float wx1 = px - fx, wy1 = py - fy, wz1 = pz - fz;
            const float wx0 = 1.0f - wx1, wy0 = 1.0f - wy1, wz0 = 1.0f - wz1;
            const uint32_t ix = (uint32_t)fx, iy = (uint32_t)fy, iz = (uint32_t)fz;

            const uint32_t dx = (uint32_t)(res * res);
            const uint32_t dy = (uint32_t)res;
            const uint32_t base = off + ix * dx + iy * dy + iz;

            float ax = 0.0f, ay = 0.0f;
            {
                float2 e0 = emb[base];           float2 e1 = emb[base + 1];
                float wxy = wx0 * wy0;
                ax += wxy * (wz0 * e0.x + wz1 * e1.x); ay += wxy * (wz0 * e0.y + wz1 * e1.y);
            }
            {
                float2 e0 = emb[base + dy];      float2 e1 = emb[base + dy + 1];
                float wxy = wx0 * wy1;
                ax += wxy * (wz0 * e0.x + wz1 * e1.x); ay += wxy * (wz0 * e0.y + wz1 * e1.y);
            }
            {
                float2 e0 = emb[base + dx];      float2 e1 = emb[base + dx + 1];
                float wxy = wx1 * wy0;
                ax += wxy * (wz0 * e0.x + wz1 * e1.x); ay += wxy * (wz0 * e0.y + wz1 * e1.y);
            }
            {
                float2 e0 = emb[base + dx + dy]; float2 e1 = emb[base + dx + dy + 1];
                float wxy = wx1 * wy1;
                ax += wxy * (wz0 * e0.x + wz1 * e1.x); ay += wxy * (wz0 * e0.y + wz1 * e1.y);
            }
            o[2 * l]     = ax;
            o[2 * l + 1] = ay;
        }
        float4* ov = (float4*)(out + (size_t)b * 32);
#pragma unroll
        for (int i = 0; i < 4; ++i)
            ov[i] = make_float4(o[4 * i + 0], o[4 * i + 1], o[4 * i + 2], o[4 * i + 3]);
    } else {
        const int l0 = 6 + 2 * y;
        const float2 ra = hash_level(emb, l0,     xn, yn, zn);
        const float2 rb = hash_level(emb, l0 + 1, xn, yn, zn);
        float4* op = (float4*)(out + (size_t)b * 32 + 2 * l0);
        *op = make_float4(ra.x, ra.y, rb.x, rb.y);
    }
}

extern "C" void kernel_launch(void* const* d_in, const int* in_sizes, int n_in,
                              void* d_out, int out_size, void* d_ws, size_t ws_size,
                              hipStream_t stream) {
    const float*  xyz = (const float*)d_in[0];
    const float2* emb = (const float2*)d_in[1];
    const float*  mn  = (const float*)d_in[2];
    const float*  mx  = (const float*)d_in[3];
    float* out = (float*)d_out;

    const int npts = in_sizes[0] / 3;          // 1<<20
    const int block = 256;
    const int grid_x = (npts + block - 1) / block;

    const size_t ws_needed = (size_t)D_CTOT * 64u;   // 62.3 MB

    if (ws_size >= ws_needed && d_ws != nullptr) {
        float2* ws = (float2*)d_ws;
        const int prep_gx = (int)((PREP_MAXTASK + 255u) / 256u);   // 7704
        hipLaunchKernelGGL(prep_cells, dim3(prep_gx, 8), dim3(256), 0, stream, emb, ws);
        hipLaunchKernelGGL(hashgrid_cell, dim3(grid_x, 5), dim3(block), 0, stream,
                           xyz, emb, ws, mn, mx, out, npts);
    } else {
        hipLaunchKernelGGL(hashgrid_direct, dim3(grid_x, 5), dim3(block), 0, stream,
                           xyz, emb, mn, mx, out, npts);
    }
}